// Round 1
// baseline (65.083 us; speedup 1.0000x reference)
//
#include <hip/hip_runtime.h>

// Problem constants (from reference)
#define B_ROWS 4096
#define C_ROWS 16384
#define F_DIM  512
#define WEIGHT 0.0005
#define EPS 1e-12f
#define CLAMP_MAX 1e12f

// One 64-lane wave per row b:
//   sx  = sum x[b,f]^2
//   sc  = sum centers[lab,f]^2
//   sxc = sum x[b,f]*centers[lab,f]
// d = sx/nx^2 + sc/nc^2 - 2*sxc/(nx*nc), clamped, atomically accumulated.
__global__ void __launch_bounds__(256)
center_loss_rows(const float* __restrict__ x,
                 const int*   __restrict__ labels,
                 const float* __restrict__ centers,
                 float*       __restrict__ acc) {
    const int wave = threadIdx.x >> 6;            // 0..3
    const int lane = threadIdx.x & 63;
    const int row  = blockIdx.x * 4 + wave;       // B_ROWS rows total
    if (row >= B_ROWS) return;

    const float* xr = x + (size_t)row * F_DIM;
    const int lab = labels[row];
    const float* cr = centers + (size_t)lab * F_DIM;

    float sx = 0.f, sc = 0.f, sxc = 0.f;
    // 512 floats / 64 lanes = 8 floats/lane = 2x float4, coalesced segments
    #pragma unroll
    for (int k = 0; k < 2; ++k) {
        const int idx = lane * 4 + k * 256;       // 0..255 then 256..511
        const float4 xv = *reinterpret_cast<const float4*>(xr + idx);
        const float4 cv = *reinterpret_cast<const float4*>(cr + idx);
        sx  += xv.x * xv.x + xv.y * xv.y + xv.z * xv.z + xv.w * xv.w;
        sc  += cv.x * cv.x + cv.y * cv.y + cv.z * cv.z + cv.w * cv.w;
        sxc += xv.x * cv.x + xv.y * cv.y + xv.z * cv.z + xv.w * cv.w;
    }
    // 64-lane butterfly reduction
    #pragma unroll
    for (int off = 32; off > 0; off >>= 1) {
        sx  += __shfl_down(sx,  off);
        sc  += __shfl_down(sc,  off);
        sxc += __shfl_down(sxc, off);
    }
    if (lane == 0) {
        const float nx = fmaxf(sqrtf(sx), EPS);
        const float nc = fmaxf(sqrtf(sc), EPS);
        const float x2  = sx  / (nx * nx);
        const float c2  = sc  / (nc * nc);
        const float dot = sxc / (nx * nc);
        float d = x2 + c2 - 2.f * dot;
        d = fminf(fmaxf(d, EPS), CLAMP_MAX);
        atomicAdd(acc, d);     // device-scope by default on CDNA
    }
}

__global__ void center_loss_finalize(const float* __restrict__ acc,
                                     float* __restrict__ out) {
    if (threadIdx.x == 0 && blockIdx.x == 0) {
        // masked-out entries: B*(C-1) zeros clamped up to 1e-12 each
        const double masked = (double)B_ROWS * (double)(C_ROWS - 1) * 1e-12;
        const double loss = WEIGHT * (((double)acc[0] + masked) / (double)B_ROWS);
        out[0] = (float)loss;
    }
}

extern "C" void kernel_launch(void* const* d_in, const int* in_sizes, int n_in,
                              void* d_out, int out_size, void* d_ws, size_t ws_size,
                              hipStream_t stream) {
    const float* x       = (const float*)d_in[0];
    const int*   labels  = (const int*)d_in[1];
    const float* centers = (const float*)d_in[2];
    float* out = (float*)d_out;
    float* acc = (float*)d_ws;

    // zero the accumulator (capture-safe async memset on the stream)
    hipMemsetAsync(acc, 0, sizeof(float), stream);

    // 4 waves (rows) per 256-thread block
    const int blocks = B_ROWS / 4;   // 1024
    center_loss_rows<<<blocks, 256, 0, stream>>>(x, labels, centers, acc);
    center_loss_finalize<<<1, 64, 0, stream>>>(acc, out);
}

// Round 2
// 11.309 us; speedup vs baseline: 5.7548x; 5.7548x over previous
//
#include <hip/hip_runtime.h>

// Problem constants (from reference)
#define B_ROWS 4096
#define C_ROWS 16384
#define F_DIM  512
#define WEIGHT 0.0005
#define EPS 1e-12f
#define CLAMP_MAX 1e12f

#define BLOCKS 1024   // 4 rows per block (1 row per wave)

// One 64-lane wave per row b:
//   sx  = sum x[b,f]^2
//   sc  = sum centers[lab,f]^2
//   sxc = sum x[b,f]*centers[lab,f]
// d = sx/nx^2 + sc/nc^2 - 2*sxc/(nx*nc), clamped.
// Block reduces its 4 rows in LDS -> one partial per block (NO atomics).
__global__ void __launch_bounds__(256)
center_loss_rows(const float* __restrict__ x,
                 const int*   __restrict__ labels,
                 const float* __restrict__ centers,
                 float*       __restrict__ partial) {
    const int wave = threadIdx.x >> 6;            // 0..3
    const int lane = threadIdx.x & 63;
    const int row  = blockIdx.x * 4 + wave;       // exactly B_ROWS rows

    const float* xr = x + (size_t)row * F_DIM;
    const int lab = labels[row];
    const float* cr = centers + (size_t)lab * F_DIM;

    float sx = 0.f, sc = 0.f, sxc = 0.f;
    // 512 floats / 64 lanes = 8 floats/lane = 2x float4, coalesced segments
    #pragma unroll
    for (int k = 0; k < 2; ++k) {
        const int idx = lane * 4 + k * 256;       // 0..255 then 256..511
        const float4 xv = *reinterpret_cast<const float4*>(xr + idx);
        const float4 cv = *reinterpret_cast<const float4*>(cr + idx);
        sx  += xv.x * xv.x + xv.y * xv.y + xv.z * xv.z + xv.w * xv.w;
        sc  += cv.x * cv.x + cv.y * cv.y + cv.z * cv.z + cv.w * cv.w;
        sxc += xv.x * cv.x + xv.y * cv.y + xv.z * cv.z + xv.w * cv.w;
    }
    // 64-lane butterfly reduction
    #pragma unroll
    for (int off = 32; off > 0; off >>= 1) {
        sx  += __shfl_down(sx,  off);
        sc  += __shfl_down(sc,  off);
        sxc += __shfl_down(sxc, off);
    }

    __shared__ float wsum[4];
    if (lane == 0) {
        const float nx = fmaxf(sqrtf(sx), EPS);
        const float nc = fmaxf(sqrtf(sc), EPS);
        const float x2  = sx  / (nx * nx);
        const float c2  = sc  / (nc * nc);
        const float dot = sxc / (nx * nc);
        float d = x2 + c2 - 2.f * dot;
        d = fminf(fmaxf(d, EPS), CLAMP_MAX);
        wsum[wave] = d;
    }
    __syncthreads();
    if (threadIdx.x == 0) {
        partial[blockIdx.x] = wsum[0] + wsum[1] + wsum[2] + wsum[3];
    }
}

// Sum 1024 block partials, add masked-clamp constant, scale.
__global__ void __launch_bounds__(256)
center_loss_finalize(const float* __restrict__ partial,
                     float* __restrict__ out) {
    const int t    = threadIdx.x;
    const int lane = t & 63;
    const int wave = t >> 6;

    float s = partial[t] + partial[t + 256] + partial[t + 512] + partial[t + 768];
    #pragma unroll
    for (int off = 32; off > 0; off >>= 1) {
        s += __shfl_down(s, off);
    }
    __shared__ float wsum[4];
    if (lane == 0) wsum[wave] = s;
    __syncthreads();
    if (t == 0) {
        const double total = (double)wsum[0] + wsum[1] + wsum[2] + wsum[3];
        // masked-out entries: B*(C-1) zeros clamped up to 1e-12 each
        const double masked = (double)B_ROWS * (double)(C_ROWS - 1) * 1e-12;
        out[0] = (float)(WEIGHT * ((total + masked) / (double)B_ROWS));
    }
}

extern "C" void kernel_launch(void* const* d_in, const int* in_sizes, int n_in,
                              void* d_out, int out_size, void* d_ws, size_t ws_size,
                              hipStream_t stream) {
    const float* x       = (const float*)d_in[0];
    const int*   labels  = (const int*)d_in[1];
    const float* centers = (const float*)d_in[2];
    float* out     = (float*)d_out;
    float* partial = (float*)d_ws;   // 1024 floats, fully overwritten each call

    center_loss_rows<<<BLOCKS, 256, 0, stream>>>(x, labels, centers, partial);
    center_loss_finalize<<<1, 256, 0, stream>>>(partial, out);
}